// Round 9
// baseline (136.018 us; speedup 1.0000x reference)
//
#include <hip/hip_runtime.h>
#include <hip/hip_bf16.h>
#include <stdint.h>

#define T_STEPS 8192
#define NN 64
#define FF 128
#define HH 128
#define OO 128

typedef _Float16 f16;
typedef __attribute__((ext_vector_type(8))) _Float16 f16x8;
typedef __attribute__((ext_vector_type(4))) _Float16 f16x4;
typedef __attribute__((ext_vector_type(4))) float f32x4;

#define WC_PITCH 136   // f16 units, 2-way bank aliasing max
#define NM_PITCH 72
#define H2_PITCH 72

// ---------------- prep: norm (f16) + bc = b_enc @ W_gcn (f32) ----------------
__global__ void prep_norm_kernel(const int* __restrict__ src, const int* __restrict__ dst, int E,
                                 const float* __restrict__ benc, const float* __restrict__ wgcn,
                                 f16* __restrict__ normg, float* __restrict__ bcg)
{
    __shared__ float A[NN * NN];
    __shared__ float din[NN], dout[NN];
    const int tid = threadIdx.x;
    for (int i = tid; i < NN * NN; i += 256) A[i] = 0.0f;
    __syncthreads();
    for (int e = tid; e < E; e += 256) atomicAdd(&A[dst[e] * NN + src[e]], 1.0f);
    __syncthreads();
    if (tid < NN) A[tid * NN + tid] += 1.0f;
    __syncthreads();
    if (tid < NN) {               // deg_in[i] = row sum
        float s = 0.f;
        for (int j = 0; j < NN; ++j) s += A[tid * NN + j];
        din[tid] = s;
    } else if (tid < 2 * NN) {    // deg_out[j] = col sum
        int j = tid - NN;
        float s = 0.f;
        for (int i = 0; i < NN; ++i) s += A[i * NN + j];
        dout[j] = s;
    }
    __syncthreads();
    if (tid < NN) {
        float ri = rsqrtf(din[tid]);
        for (int j = 0; j < NN; ++j)
            normg[tid * NN + j] = (f16)(A[tid * NN + j] * ri * rsqrtf(dout[j]));
    }
    if (tid >= 128) {             // bc[o] = b_enc @ W_gcn
        int o = tid - 128;
        float s = 0.f;
        for (int h = 0; h < HH; ++h) s += benc[h] * wgcn[h * OO + o];
        bcg[o] = s;
    }
}

// ---------------- prep: WcT[o][f] = (W_enc @ W_gcn)^T (f16) ----------------
__global__ void prep_wc_kernel(const float* __restrict__ wenc, const float* __restrict__ wgcn,
                               f16* __restrict__ wctg)
{
    int o = blockIdx.x * 2 + (threadIdx.x >> 7);
    int f = threadIdx.x & 127;
    float s = 0.f;
    for (int h = 0; h < HH; ++h) s += wenc[f * HH + h] * wgcn[h * OO + o];
    wctg[o * FF + f] = (f16)s;
}

// ---------------- fused main: one t-step PER WAVE, no in-loop barriers ----------------
// out[t] = norm @ (x_t @ Wc + 1*bc) + 1*bgcn, each wave fully independent.
__global__ __launch_bounds__(256, 2) void fused_kernel(
    const float* __restrict__ x, const f16* __restrict__ normg,
    const f16* __restrict__ wctg, const float* __restrict__ bcg,
    const float* __restrict__ bgcn, float* __restrict__ out)
{
    __shared__ f16 wcsh[OO * WC_PITCH];   // WcT staged (34816 B)
    __shared__ f16 nsh[NN * NM_PITCH];    // norm staged (9216 B)
    __shared__ float bcsh[OO];            // 512 B
    __shared__ float bgsh[OO];            // 512 B
    __shared__ f16 h2b[4][32 * H2_PITCH]; // per-wave transpose buf (4x4608 B)
    // total ~63.5 KB -> 2 blocks/CU

    const int tid = threadIdx.x;
    const int lane = tid & 63;
    const int w = tid >> 6;
    const int l15 = lane & 15;
    const int lg = lane >> 4;

    // --- stage loop-invariants cooperatively, ONE barrier per block lifetime ---
#pragma unroll
    for (int r = 0; r < 8; ++r) {
        int c = tid + 256 * r;            // 2048 x 16B chunks of WcT
        int o = c >> 4, k = (c & 15) * 8;
        *(f16x8*)(wcsh + o * WC_PITCH + k) = *(const f16x8*)(wctg + o * FF + k);
    }
#pragma unroll
    for (int r = 0; r < 2; ++r) {
        int c = tid + 256 * r;            // 512 x 16B chunks of norm
        int o = c >> 3, k = (c & 7) * 8;
        *(f16x8*)(nsh + o * NM_PITCH + k) = *(const f16x8*)(normg + o * NN + k);
    }
    if (tid < 32) {
        *(f32x4*)(bcsh + tid * 4) = *(const f32x4*)(bcg + tid * 4);
    } else if (tid < 64) {
        int j = tid - 32;
        *(f32x4*)(bgsh + j * 4) = *(const f32x4*)(bgcn + j * 4);
    }
    __syncthreads();   // the only block-wide barrier

    const int t = blockIdx.x * 4 + w;
    const float* xt = x + (size_t)t * (NN * FF);

    // --- phase 1: load x_t directly in A-frag layout, convert to f16 ---
    f32x4 raw[4][4][2];
#pragma unroll
    for (int rt = 0; rt < 4; ++rt)
#pragma unroll
        for (int kk = 0; kk < 4; ++kk) {
            const float* p = xt + (rt * 16 + l15) * FF + kk * 32 + lg * 8;
            raw[rt][kk][0] = *(const f32x4*)(p);
            raw[rt][kk][1] = *(const f32x4*)(p + 4);
        }
    f16x8 af[4][4];
#pragma unroll
    for (int rt = 0; rt < 4; ++rt)
#pragma unroll
        for (int kk = 0; kk < 4; ++kk) {
            f32x4 a0 = raw[rt][kk][0], a1 = raw[rt][kk][1];
            f16x8 v;
            v[0] = (f16)a0[0]; v[1] = (f16)a0[1]; v[2] = (f16)a0[2]; v[3] = (f16)a0[3];
            v[4] = (f16)a1[0]; v[5] = (f16)a1[1]; v[6] = (f16)a1[2]; v[7] = (f16)a1[3];
            af[rt][kk] = v;
        }

    // --- acc2 (full 64x128 output of this t) init with bgcn bias ---
    f32x4 acc2[8][4];
#pragma unroll
    for (int m8 = 0; m8 < 8; ++m8) {
        f32x4 bg = *(const f32x4*)(bgsh + m8 * 16 + lg * 4);
#pragma unroll
        for (int nt = 0; nt < 4; ++nt) acc2[m8][nt] = bg;
    }

    f16* hb = h2b[w];   // wave-private

    // --- per 32-column group: matmul1 -> transpose -> matmul2 accumulate ---
#pragma unroll
    for (int cg = 0; cg < 4; ++cg) {
#pragma unroll
        for (int ct2 = 0; ct2 < 2; ++ct2) {
            const int col = cg * 32 + ct2 * 16 + l15;
            float bv = bcsh[col];
            f32x4 acc1[4];
#pragma unroll
            for (int rt = 0; rt < 4; ++rt) {
                acc1[rt][0] = bv; acc1[rt][1] = bv; acc1[rt][2] = bv; acc1[rt][3] = bv;
            }
#pragma unroll
            for (int kk = 0; kk < 4; ++kk) {
                f16x8 wcf = *(const f16x8*)(wcsh + col * WC_PITCH + kk * 32 + lg * 8);
#pragma unroll
                for (int rt = 0; rt < 4; ++rt)
                    acc1[rt] = __builtin_amdgcn_mfma_f32_16x16x32_f16(
                        af[rt][kk], wcf, acc1[rt], 0, 0, 0);
            }
            // transpose: h2 col -> row of hb
#pragma unroll
            for (int rt = 0; rt < 4; ++rt) {
                f16x4 hv;
#pragma unroll
                for (int r = 0; r < 4; ++r) hv[r] = (f16)acc1[rt][r];
                *(f16x4*)(hb + (ct2 * 16 + l15) * H2_PITCH + rt * 16 + lg * 4) = hv;
            }
        }
        // matmul2 for this cg: D = h2cg^T * norm^T (K = 64 nodes)
#pragma unroll
        for (int kk2 = 0; kk2 < 2; ++kk2) {
            f16x8 nf[4];
#pragma unroll
            for (int nt = 0; nt < 4; ++nt)
                nf[nt] = *(const f16x8*)(nsh + (nt * 16 + l15) * NM_PITCH + kk2 * 32 + lg * 8);
            f16x8 a2[2];
#pragma unroll
            for (int mt = 0; mt < 2; ++mt)
                a2[mt] = *(const f16x8*)(hb + (mt * 16 + l15) * H2_PITCH + kk2 * 32 + lg * 8);
#pragma unroll
            for (int mt = 0; mt < 2; ++mt)
#pragma unroll
                for (int nt = 0; nt < 4; ++nt)
                    acc2[cg * 2 + mt][nt] = __builtin_amdgcn_mfma_f32_16x16x32_f16(
                        a2[mt], nf[nt], acc2[cg * 2 + mt][nt], 0, 0, 0);
        }
    }

    // --- epilogue: full 512B rows, float4 stores ---
    float* op = out + (size_t)t * (NN * OO);
#pragma unroll
    for (int nt = 0; nt < 4; ++nt)
#pragma unroll
        for (int m8 = 0; m8 < 8; ++m8)
            *(f32x4*)(op + (nt * 16 + l15) * OO + m8 * 16 + lg * 4) = acc2[m8][nt];
}

extern "C" void kernel_launch(void* const* d_in, const int* in_sizes, int n_in,
                              void* d_out, int out_size, void* d_ws, size_t ws_size,
                              hipStream_t stream)
{
    const float* x    = (const float*)d_in[0];
    const float* wenc = (const float*)d_in[1];
    const float* benc = (const float*)d_in[2];
    const float* wgcn = (const float*)d_in[3];
    const float* bgcn = (const float*)d_in[4];
    const int*   src  = (const int*)d_in[5];
    const int*   dst  = (const int*)d_in[6];
    const int E = in_sizes[5];

    // workspace: WcT f16 [128*128] (32768 B) | norm f16 [64*64] (8192 B) | bc f32 [128] (512 B)
    f16*   wctg  = (f16*)d_ws;
    f16*   normg = (f16*)((char*)d_ws + 32768);
    float* bcg   = (float*)((char*)d_ws + 32768 + 8192);

    prep_norm_kernel<<<1, 256, 0, stream>>>(src, dst, E, benc, wgcn, normg, bcg);
    prep_wc_kernel<<<OO / 2, 256, 0, stream>>>(wenc, wgcn, wctg);
    fused_kernel<<<T_STEPS / 4, 256, 0, stream>>>(x, normg, wctg, bcg, bgcn, (float*)d_out);
}

// Round 10
// 132.081 us; speedup vs baseline: 1.0298x; 1.0298x over previous
//
#include <hip/hip_runtime.h>
#include <hip/hip_bf16.h>

#define T_STEPS 8192
#define NN 64
#define FF 128
#define HH 128
#define OO 128
#define TPB_T 8

typedef _Float16 f16;
typedef __attribute__((ext_vector_type(8))) _Float16 f16x8;
typedef __attribute__((ext_vector_type(4))) _Float16 f16x4;
typedef __attribute__((ext_vector_type(4))) float f32x4;

// LDS pitches chosen for <=2-way bank aliasing on ds_read_b128 (free per m136)
#define XH_PITCH 136   // f16 units; stride 68 dwords -> bank step 4, 2-way
#define H2_PITCH 72    // f16 units; stride 36 dwords -> bank step 4, 2-way
#define NM_PITCH 72    // norm tile in LDS, same geometry

// Raw barrier with no vmcnt drain and no "memory" clobber (see r6 notes).
#define BAR_LDS() do {                                        \
    __builtin_amdgcn_sched_barrier(0);                        \
    asm volatile("s_waitcnt lgkmcnt(0)");                     \
    __builtin_amdgcn_s_barrier();                             \
    __builtin_amdgcn_sched_barrier(0);                        \
} while (0)

// ---------------- prep: norm (f16) + bc = b_enc @ W_gcn (f32) ----------------
__global__ void prep_norm_kernel(const int* __restrict__ src, const int* __restrict__ dst, int E,
                                 const float* __restrict__ benc, const float* __restrict__ wgcn,
                                 f16* __restrict__ normg, float* __restrict__ bcg)
{
    __shared__ float A[NN * NN];
    __shared__ float din[NN], dout[NN];
    const int tid = threadIdx.x;
    for (int i = tid; i < NN * NN; i += 256) A[i] = 0.0f;
    __syncthreads();
    for (int e = tid; e < E; e += 256) atomicAdd(&A[dst[e] * NN + src[e]], 1.0f);
    __syncthreads();
    if (tid < NN) A[tid * NN + tid] += 1.0f;
    __syncthreads();
    if (tid < NN) {               // deg_in[i] = row sum
        float s = 0.f;
        for (int j = 0; j < NN; ++j) s += A[tid * NN + j];
        din[tid] = s;
    } else if (tid < 2 * NN) {    // deg_out[j] = col sum
        int j = tid - NN;
        float s = 0.f;
        for (int i = 0; i < NN; ++i) s += A[i * NN + j];
        dout[j] = s;
    }
    __syncthreads();
    if (tid < NN) {
        float ri = rsqrtf(din[tid]);
        for (int j = 0; j < NN; ++j)
            normg[tid * NN + j] = (f16)(A[tid * NN + j] * ri * rsqrtf(dout[j]));
    }
    if (tid >= 128) {             // bc[o] = b_enc @ W_gcn
        int o = tid - 128;
        float s = 0.f;
        for (int h = 0; h < HH; ++h) s += benc[h] * wgcn[h * OO + o];
        bcg[o] = s;
    }
}

// ---------------- prep: WcT[o][f] = (W_enc @ W_gcn)^T (f16) ----------------
__global__ void prep_wc_kernel(const float* __restrict__ wenc, const float* __restrict__ wgcn,
                               f16* __restrict__ wctg)
{
    int o = blockIdx.x * 2 + (threadIdx.x >> 7);
    int f = threadIdx.x & 127;
    float s = 0.f;
    for (int h = 0; h < HH; ++h) s += wenc[f * HH + h] * wgcn[h * OO + o];
    wctg[o * FF + f] = (f16)s;
}

// ---------------- fused main: out[t] = norm @ (x[t] @ Wc + 1*bc) + 1*bgcn ----------------
__global__ __launch_bounds__(256, 2) void fused_kernel(
    const float* __restrict__ x, const f16* __restrict__ normg,
    const f16* __restrict__ wctg, const float* __restrict__ bcg,
    const float* __restrict__ bgcn, float* __restrict__ out)
{
    __shared__ f16 xh[NN * XH_PITCH];    // x_t as f16, padded  (17408 B)
    __shared__ f16 h2t[OO * H2_PITCH];   // h2 transposed [col][node] (18432 B)
    __shared__ f16 nsh[NN * NM_PITCH];   // norm staged in LDS (9216 B)

    const int tid = threadIdx.x;
    const int lane = tid & 63;
    const int w = tid >> 6;        // wave 0..3 -> output cols w*32..w*32+31
    const int l15 = lane & 15;
    const int lg = lane >> 4;      // 0..3

    // stage norm into LDS once (covered by the first barrier)
    for (int c = tid; c < (NN * NN) / 8; c += 256) {
        int row = c >> 3, cb = (c & 7) * 8;
        *(f16x8*)(nsh + row * NM_PITCH + cb) = *(const f16x8*)(normg + row * NN + cb);
    }

    // loop-invariant register state
    f16x8 wcf[2][4];               // Wc B-frags for this wave's col slice (32 VGPR)
#pragma unroll
    for (int ct = 0; ct < 2; ++ct)
#pragma unroll
        for (int kk = 0; kk < 4; ++kk)
            wcf[ct][kk] = *(const f16x8*)(wctg + (w * 32 + ct * 16 + l15) * FF + kk * 32 + lg * 8);

    f32x4 bcs[2];                  // bc splat per ct (acc1 init)
#pragma unroll
    for (int ct = 0; ct < 2; ++ct) {
        float v = bcg[w * 32 + ct * 16 + l15];
        bcs[ct][0] = v; bcs[ct][1] = v; bcs[ct][2] = v; bcs[ct][3] = v;
    }
    f32x4 bgf[2];                  // bgcn frag per ct (acc2 init)
#pragma unroll
    for (int ct = 0; ct < 2; ++ct)
        bgf[ct] = *(const f32x4*)(bgcn + w * 32 + ct * 16 + lg * 4);

    const int t0 = blockIdx.x * TPB_T;

    // depth-2 register prefetch: two named buffers (rule #20: no runtime indexing)
    float4 raA[8], raB[8];
    {
        const float4* xp0 = (const float4*)(x + (size_t)t0 * (NN * FF));
        const float4* xp1 = xp0 + (NN * FF) / 4;
#pragma unroll
        for (int ii = 0; ii < 4; ++ii) {
            int c = tid + 256 * ii;
            raA[2 * ii]     = xp0[2 * c];
            raA[2 * ii + 1] = xp0[2 * c + 1];
        }
#pragma unroll
        for (int ii = 0; ii < 4; ++ii) {
            int c = tid + 256 * ii;
            raB[2 * ii]     = xp1[2 * c];
            raB[2 * ii + 1] = xp1[2 * c + 1];
        }
    }

    // one t-iteration: consume `rau`, refill it for t+2
    auto body = [&](float4 (&rau)[8], int i) {
        const int t = t0 + i;

        // S1: convert + stage x_t into LDS
#pragma unroll
        for (int ii = 0; ii < 4; ++ii) {
            int c = tid + 256 * ii;
            int row = c >> 4, k0 = (c & 15) * 8;
            float4 a = rau[2 * ii], b = rau[2 * ii + 1];
            f16x8 v;
            v[0] = (f16)a.x; v[1] = (f16)a.y; v[2] = (f16)a.z; v[3] = (f16)a.w;
            v[4] = (f16)b.x; v[5] = (f16)b.y; v[6] = (f16)b.z; v[7] = (f16)b.w;
            *(f16x8*)(xh + row * XH_PITCH + k0) = v;
        }
        BAR_LDS();         // xh (and, first iter, nsh) ready

        // S3: refill rau for t+2
        if (i + 2 < TPB_T) {
            const float4* xq = (const float4*)(x + (size_t)(t + 2) * (NN * FF));
#pragma unroll
            for (int ii = 0; ii < 4; ++ii) {
                int c = tid + 256 * ii;
                rau[2 * ii]     = xq[2 * c];
                rau[2 * ii + 1] = xq[2 * c + 1];
            }
        }
        __builtin_amdgcn_sched_barrier(0);   // pin load issue before the MFMA cluster

        // S4: matmul1  h2'[64, w-cols] = x_t @ Wc + 1*bc   (bias via acc init)
        f32x4 acc1[4][2];
#pragma unroll
        for (int rt = 0; rt < 4; ++rt)
#pragma unroll
            for (int ct = 0; ct < 2; ++ct)
                acc1[rt][ct] = bcs[ct];
#pragma unroll
        for (int kk = 0; kk < 4; ++kk) {
            f16x8 af[4];
#pragma unroll
            for (int rt = 0; rt < 4; ++rt)
                af[rt] = *(const f16x8*)(xh + (rt * 16 + l15) * XH_PITCH + kk * 32 + lg * 8);
#pragma unroll
            for (int rt = 0; rt < 4; ++rt)
#pragma unroll
                for (int ct = 0; ct < 2; ++ct)
                    acc1[rt][ct] = __builtin_amdgcn_mfma_f32_16x16x32_f16(
                        af[rt], wcf[ct][kk], acc1[rt][ct], 0, 0, 0);
        }
        BAR_LDS();         // all waves done reading xh

        // S5: per-wave transpose h2' -> LDS [col][node] (wave-private cols, no barrier)
#pragma unroll
        for (int rt = 0; rt < 4; ++rt)
#pragma unroll
            for (int ct = 0; ct < 2; ++ct) {
                f16x4 hv;
#pragma unroll
                for (int r = 0; r < 4; ++r) hv[r] = (f16)acc1[rt][ct][r];
                *(f16x4*)(h2t + (w * 32 + ct * 16 + l15) * H2_PITCH + rt * 16 + lg * 4) = hv;
            }

        // S7: matmul2 swapped: D = h2'^T * norm^T  (lane -> 4 consecutive out cols)
        f32x4 acc2[2][4];
#pragma unroll
        for (int ct = 0; ct < 2; ++ct)
#pragma unroll
            for (int rt = 0; rt < 4; ++rt)
                acc2[ct][rt] = bgf[ct];
#pragma unroll
        for (int kk = 0; kk < 2; ++kk) {
            f16x8 bf[2];
#pragma unroll
            for (int ct = 0; ct < 2; ++ct)
                bf[ct] = *(const f16x8*)(h2t + (w * 32 + ct * 16 + l15) * H2_PITCH + kk * 32 + lg * 8);
            f16x8 nl[4];
#pragma unroll
            for (int rt = 0; rt < 4; ++rt)
                nl[rt] = *(const f16x8*)(nsh + (rt * 16 + l15) * NM_PITCH + kk * 32 + lg * 8);
#pragma unroll
            for (int ct = 0; ct < 2; ++ct)
#pragma unroll
                for (int rt = 0; rt < 4; ++rt)
                    acc2[ct][rt] = __builtin_amdgcn_mfma_f32_16x16x32_f16(
                        bf[ct], nl[rt], acc2[ct][rt], 0, 0, 0);
        }

        // epilogue: NONTEMPORAL float4 stores (full 128B lines). The 268 MB
        // output stream is never re-read; nt stores skip L2/L3 allocation,
        // leaving the caches to the x read stream.
        float* op = out + (size_t)t * (NN * OO);
#pragma unroll
        for (int rt = 0; rt < 4; ++rt)
#pragma unroll
            for (int ct = 0; ct < 2; ++ct) {
                f32x4* dst = (f32x4*)(op + (rt * 16 + l15) * OO + w * 32 + ct * 16 + lg * 4);
                __builtin_nontemporal_store(acc2[ct][rt], dst);
            }
    };

#pragma unroll 1
    for (int i = 0; i < TPB_T; i += 2) {
        body(raA, i);
        body(raB, i + 1);
    }
}

extern "C" void kernel_launch(void* const* d_in, const int* in_sizes, int n_in,
                              void* d_out, int out_size, void* d_ws, size_t ws_size,
                              hipStream_t stream)
{
    const float* x    = (const float*)d_in[0];
    const float* wenc = (const float*)d_in[1];
    const float* benc = (const float*)d_in[2];
    const float* wgcn = (const float*)d_in[3];
    const float* bgcn = (const float*)d_in[4];
    const int*   src  = (const int*)d_in[5];
    const int*   dst  = (const int*)d_in[6];
    const int E = in_sizes[5];

    // workspace: WcT f16 [128*128] (32768 B) | norm f16 [64*64] (8192 B) | bc f32 [128] (512 B)
    f16*   wctg  = (f16*)d_ws;
    f16*   normg = (f16*)((char*)d_ws + 32768);
    float* bcg   = (float*)((char*)d_ws + 32768 + 8192);

    prep_norm_kernel<<<1, 256, 0, stream>>>(src, dst, E, benc, wgcn, normg, bcg);
    prep_wc_kernel<<<OO / 2, 256, 0, stream>>>(wenc, wgcn, wctg);
    fused_kernel<<<T_STEPS / TPB_T, 256, 0, stream>>>(x, normg, wctg, bcg, bgcn, (float*)d_out);
}

// Round 15
// 106.024 us; speedup vs baseline: 1.2829x; 1.2458x over previous
//
#include <hip/hip_runtime.h>
#include <hip/hip_bf16.h>

#define T_STEPS 8192
#define NN 64
#define FF 128
#define HH 128
#define OO 128
#define TPB_T 8

typedef _Float16 f16;
typedef __attribute__((ext_vector_type(8))) _Float16 f16x8;
typedef __attribute__((ext_vector_type(4))) _Float16 f16x4;
typedef __attribute__((ext_vector_type(4))) float f32x4;

// LDS pitches chosen for <=2-way bank aliasing on ds_read_b128 (free per m136)
#define XH_PITCH 136   // f16 units
#define H2_PITCH 72    // f16 units
#define NM_PITCH 72    // norm tile

// Raw barrier with no vmcnt drain and no "memory" clobber (see r6 notes).
#define BAR_LDS() do {                                        \
    __builtin_amdgcn_sched_barrier(0);                        \
    asm volatile("s_waitcnt lgkmcnt(0)");                     \
    __builtin_amdgcn_s_barrier();                             \
    __builtin_amdgcn_sched_barrier(0);                        \
} while (0)

// ---------------- prep: norm (f16) + bc = b_enc @ W_gcn (f32) ----------------
__global__ void prep_norm_kernel(const int* __restrict__ src, const int* __restrict__ dst, int E,
                                 const float* __restrict__ benc, const float* __restrict__ wgcn,
                                 f16* __restrict__ normg, float* __restrict__ bcg)
{
    __shared__ float A[NN * NN];
    __shared__ float din[NN], dout[NN];
    const int tid = threadIdx.x;
    for (int i = tid; i < NN * NN; i += 256) A[i] = 0.0f;
    __syncthreads();
    for (int e = tid; e < E; e += 256) atomicAdd(&A[dst[e] * NN + src[e]], 1.0f);
    __syncthreads();
    if (tid < NN) A[tid * NN + tid] += 1.0f;
    __syncthreads();
    if (tid < NN) {               // deg_in[i] = row sum
        float s = 0.f;
        for (int j = 0; j < NN; ++j) s += A[tid * NN + j];
        din[tid] = s;
    } else if (tid < 2 * NN) {    // deg_out[j] = col sum
        int j = tid - NN;
        float s = 0.f;
        for (int i = 0; i < NN; ++i) s += A[i * NN + j];
        dout[j] = s;
    }
    __syncthreads();
    if (tid < NN) {
        float ri = rsqrtf(din[tid]);
        for (int j = 0; j < NN; ++j)
            normg[tid * NN + j] = (f16)(A[tid * NN + j] * ri * rsqrtf(dout[j]));
    }
    if (tid >= 128) {             // bc[o] = b_enc @ W_gcn
        int o = tid - 128;
        float s = 0.f;
        for (int h = 0; h < HH; ++h) s += benc[h] * wgcn[h * OO + o];
        bcg[o] = s;
    }
}

// ---------------- prep: WcT[o][f] = (W_enc @ W_gcn)^T (f16) ----------------
__global__ void prep_wc_kernel(const float* __restrict__ wenc, const float* __restrict__ wgcn,
                               f16* __restrict__ wctg)
{
    int o = blockIdx.x * 2 + (threadIdx.x >> 7);
    int f = threadIdx.x & 127;
    float s = 0.f;
    for (int h = 0; h < HH; ++h) s += wenc[f * HH + h] * wgcn[h * OO + o];
    wctg[o * FF + f] = (f16)s;
}

// ---------------- fused main: out[t] = norm @ (x[t] @ Wc + 1*bc) + 1*bgcn ----------------
__global__ __launch_bounds__(256, 2) void fused_kernel(
    const float* __restrict__ x, const f16* __restrict__ normg,
    const f16* __restrict__ wctg, const float* __restrict__ bcg,
    const float* __restrict__ bgcn, float* __restrict__ out)
{
    __shared__ f16 xh[NN * XH_PITCH];    // x_t as f16, padded  (17408 B)
    __shared__ f16 h2t[OO * H2_PITCH];   // h2 transposed [col][node] (18432 B)
    __shared__ f16 nsh[NN * NM_PITCH];   // norm staged in LDS (9216 B)
    __shared__ float obuf[NN * OO];      // out-tile bounce, XOR-swizzled (32768 B)
    // total 77824 B -> 2 blocks/CU

    const int tid = threadIdx.x;
    const int lane = tid & 63;
    const int w = tid >> 6;        // wave 0..3 -> output cols w*32..w*32+31
    const int l15 = lane & 15;
    const int lg = lane >> 4;      // 0..3

    // stage norm into LDS once (covered by the first barrier)
    for (int c = tid; c < (NN * NN) / 8; c += 256) {
        int row = c >> 3, cb = (c & 7) * 8;
        *(f16x8*)(nsh + row * NM_PITCH + cb) = *(const f16x8*)(normg + row * NN + cb);
    }

    // loop-invariant register state
    f16x8 wcf[2][4];               // Wc B-frags for this wave's col slice
#pragma unroll
    for (int ct = 0; ct < 2; ++ct)
#pragma unroll
        for (int kk = 0; kk < 4; ++kk)
            wcf[ct][kk] = *(const f16x8*)(wctg + (w * 32 + ct * 16 + l15) * FF + kk * 32 + lg * 8);

    f32x4 bcs[2];                  // bc splat per ct (acc1 init)
#pragma unroll
    for (int ct = 0; ct < 2; ++ct) {
        float v = bcg[w * 32 + ct * 16 + l15];
        bcs[ct][0] = v; bcs[ct][1] = v; bcs[ct][2] = v; bcs[ct][3] = v;
    }
    f32x4 bgf[2];                  // bgcn frag per ct (acc2 init)
#pragma unroll
    for (int ct = 0; ct < 2; ++ct)
        bgf[ct] = *(const f32x4*)(bgcn + w * 32 + ct * 16 + lg * 4);

    const int t0 = blockIdx.x * TPB_T;

    // depth-2 register prefetch: two named buffers (rule #20: no runtime indexing)
    float4 raA[8], raB[8];
    {
        const float4* xp0 = (const float4*)(x + (size_t)t0 * (NN * FF));
        const float4* xp1 = xp0 + (NN * FF) / 4;
#pragma unroll
        for (int ii = 0; ii < 4; ++ii) {
            int c = tid + 256 * ii;
            raA[2 * ii]     = xp0[2 * c];
            raA[2 * ii + 1] = xp0[2 * c + 1];
        }
#pragma unroll
        for (int ii = 0; ii < 4; ++ii) {
            int c = tid + 256 * ii;
            raB[2 * ii]     = xp1[2 * c];
            raB[2 * ii + 1] = xp1[2 * c + 1];
        }
    }

    // one t-iteration: consume `rau`, refill it for t+2
    auto body = [&](float4 (&rau)[8], int i) {
        const int t = t0 + i;

        // S1: convert + stage x_t into LDS
#pragma unroll
        for (int ii = 0; ii < 4; ++ii) {
            int c = tid + 256 * ii;
            int row = c >> 4, k0 = (c & 15) * 8;
            float4 a = rau[2 * ii], b = rau[2 * ii + 1];
            f16x8 v;
            v[0] = (f16)a.x; v[1] = (f16)a.y; v[2] = (f16)a.z; v[3] = (f16)a.w;
            v[4] = (f16)b.x; v[5] = (f16)b.y; v[6] = (f16)b.z; v[7] = (f16)b.w;
            *(f16x8*)(xh + row * XH_PITCH + k0) = v;
        }
        BAR_LDS();         // BAR1: xh ready (also covers prev iter's obuf reads)

        // S3: refill rau for t+2
        if (i + 2 < TPB_T) {
            const float4* xq = (const float4*)(x + (size_t)(t + 2) * (NN * FF));
#pragma unroll
            for (int ii = 0; ii < 4; ++ii) {
                int c = tid + 256 * ii;
                rau[2 * ii]     = xq[2 * c];
                rau[2 * ii + 1] = xq[2 * c + 1];
            }
        }
        __builtin_amdgcn_sched_barrier(0);   // pin load issue before the MFMA cluster

        // S4: matmul1  h2'[64, w-cols] = x_t @ Wc + 1*bc   (bias via acc init)
        f32x4 acc1[4][2];
#pragma unroll
        for (int rt = 0; rt < 4; ++rt)
#pragma unroll
            for (int ct = 0; ct < 2; ++ct)
                acc1[rt][ct] = bcs[ct];
#pragma unroll
        for (int kk = 0; kk < 4; ++kk) {
            f16x8 af[4];
#pragma unroll
            for (int rt = 0; rt < 4; ++rt)
                af[rt] = *(const f16x8*)(xh + (rt * 16 + l15) * XH_PITCH + kk * 32 + lg * 8);
#pragma unroll
            for (int rt = 0; rt < 4; ++rt)
#pragma unroll
                for (int ct = 0; ct < 2; ++ct)
                    acc1[rt][ct] = __builtin_amdgcn_mfma_f32_16x16x32_f16(
                        af[rt], wcf[ct][kk], acc1[rt][ct], 0, 0, 0);
        }
        BAR_LDS();         // BAR2: all waves done reading xh

        // S5: per-wave transpose h2' -> LDS [col][node] (wave-private cols, no barrier)
#pragma unroll
        for (int rt = 0; rt < 4; ++rt)
#pragma unroll
            for (int ct = 0; ct < 2; ++ct) {
                f16x4 hv;
#pragma unroll
                for (int r = 0; r < 4; ++r) hv[r] = (f16)acc1[rt][ct][r];
                *(f16x4*)(h2t + (w * 32 + ct * 16 + l15) * H2_PITCH + rt * 16 + lg * 4) = hv;
            }

        // S7: matmul2 swapped: D = h2'^T * norm^T  (lane -> 4 consecutive out cols)
        f32x4 acc2[2][4];
#pragma unroll
        for (int ct = 0; ct < 2; ++ct)
#pragma unroll
            for (int rt = 0; rt < 4; ++rt)
                acc2[ct][rt] = bgf[ct];
#pragma unroll
        for (int kk = 0; kk < 2; ++kk) {
            f16x8 bf[2];
#pragma unroll
            for (int ct = 0; ct < 2; ++ct)
                bf[ct] = *(const f16x8*)(h2t + (w * 32 + ct * 16 + l15) * H2_PITCH + kk * 32 + lg * 8);
            f16x8 nl[4];
#pragma unroll
            for (int rt = 0; rt < 4; ++rt)
                nl[rt] = *(const f16x8*)(nsh + (rt * 16 + l15) * NM_PITCH + kk * 32 + lg * 8);
#pragma unroll
            for (int ct = 0; ct < 2; ++ct)
#pragma unroll
                for (int rt = 0; rt < 4; ++rt)
                    acc2[ct][rt] = __builtin_amdgcn_mfma_f32_16x16x32_f16(
                        bf[ct], nl[rt], acc2[ct][rt], 0, 0, 0);
        }

        // S8: bounce acc2 -> obuf (XOR-swizzled dword index, <=2-way banks)
#pragma unroll
        for (int rt = 0; rt < 4; ++rt)
#pragma unroll
            for (int ct = 0; ct < 2; ++ct) {
                int row = rt * 16 + l15;
                int col = w * 32 + ct * 16 + lg * 4;
                int idx = row * 128 + (col ^ ((row & 7) << 2));
                *(f32x4*)(obuf + idx) = acc2[ct][rt];
            }
        BAR_LDS();         // BAR3: full out-tile resident in obuf

        // S9: cooperative FILL-SHAPED stores: each wave instruction writes a
        // contiguous, 1KB-aligned block (lane L -> byte L*16). No partial lines,
        // no RFO, no half-dirty evictions.
        float* opb = out + (size_t)t * (NN * OO);
#pragma unroll
        for (int j = 0; j < 8; ++j) {
            int flat = j * 1024 + tid * 4;          // dword index in 64x128 tile
            int row = flat >> 7, col = flat & 127;
            f32x4 v = *(const f32x4*)(obuf + row * 128 + (col ^ ((row & 7) << 2)));
            __builtin_nontemporal_store(v, (f32x4*)(opb + flat));
        }
    };

#pragma unroll 1
    for (int i = 0; i < TPB_T; i += 2) {
        body(raA, i);
        body(raB, i + 1);
    }
}

extern "C" void kernel_launch(void* const* d_in, const int* in_sizes, int n_in,
                              void* d_out, int out_size, void* d_ws, size_t ws_size,
                              hipStream_t stream)
{
    const float* x    = (const float*)d_in[0];
    const float* wenc = (const float*)d_in[1];
    const float* benc = (const float*)d_in[2];
    const float* wgcn = (const float*)d_in[3];
    const float* bgcn = (const float*)d_in[4];
    const int*   src  = (const int*)d_in[5];
    const int*   dst  = (const int*)d_in[6];
    const int E = in_sizes[5];

    // workspace: WcT f16 [128*128] (32768 B) | norm f16 [64*64] (8192 B) | bc f32 [128] (512 B)
    f16*   wctg  = (f16*)d_ws;
    f16*   normg = (f16*)((char*)d_ws + 32768);
    float* bcg   = (float*)((char*)d_ws + 32768 + 8192);

    prep_norm_kernel<<<1, 256, 0, stream>>>(src, dst, E, benc, wgcn, normg, bcg);
    prep_wc_kernel<<<OO / 2, 256, 0, stream>>>(wenc, wgcn, wctg);
    fused_kernel<<<T_STEPS / TPB_T, 256, 0, stream>>>(x, normg, wctg, bcg, bgcn, (float*)d_out);
}